// Round 3
// baseline (28.176 us; speedup 1.0000x reference)
//
#include <hip/hip_runtime.h>

// PoseLoss round 3: block-chunk LDS staging via global_load_lds width=16.
// Each block owns 256 samples (28 KB across 7 streams). Staging = 28 x 1KB
// wave-uniform segments, 7 async global_load_lds_dwordx4 per wave (no VGPR
// round trip, perfect 16B x 64-lane coalescing, 7-deep MLP per wave).
// 28 KB LDS -> 5 blocks/CU resident -> load/compute phases pipeline across
// blocks. Round-2 (27.2us) was load-batching-limited at VGPR=32.

#define W1_XYZ 0.3f
#define W2_XYZ 0.3f
#define W3_XYZ 1.0f
#define W1_WPQR 150.0f
#define W2_WPQR 150.0f
#define W3_WPQR 500.0f
#define EPSF 1e-12f

constexpr int B_TOTAL = 1048576;
constexpr int BLOCK = 256;
constexpr int SPB = 256;                       // samples per block
constexpr int NBLOCKS = B_TOTAL / SPB;         // 4096

// LDS layout (float offsets). Per-block chunk sizes:
// x streams: 256*3 = 768 f (3072 B = 3 segs), q streams: 1024 f (4 segs),
// gt: 1792 f (7168 B = 7 segs). Total 7168 f = 28672 B = 28 segments of 1KB.
#define X1O 0
#define X2O 768
#define X3O 1536
#define Q1O 2304
#define Q2O 3328
#define Q3O 4352
#define GO  5376
#define LDSF 7168

__global__ __launch_bounds__(BLOCK) void pose_loss_partial(
    const float* __restrict__ p1x, const float* __restrict__ p1q,
    const float* __restrict__ p2x, const float* __restrict__ p2q,
    const float* __restrict__ p3x, const float* __restrict__ p3q,
    const float* __restrict__ gt, float* __restrict__ partial)
{
    __shared__ float lds[LDSF];
    const int tid  = threadIdx.x;
    const int wid  = tid >> 6;
    const int lane = tid & 63;
    const long blk = blockIdx.x;

    // per-lane global source (contiguous 16B per lane), wave-uniform LDS dest
    const char* bx1 = (const char*)p1x + blk * 3072 + (long)lane * 16;
    const char* bx2 = (const char*)p2x + blk * 3072 + (long)lane * 16;
    const char* bx3 = (const char*)p3x + blk * 3072 + (long)lane * 16;
    const char* bq1 = (const char*)p1q + blk * 4096 + (long)lane * 16;
    const char* bq2 = (const char*)p2q + blk * 4096 + (long)lane * 16;
    const char* bq3 = (const char*)p3q + blk * 4096 + (long)lane * 16;
    const char* bg  = (const char*)gt  + blk * 7168 + (long)lane * 16;
    char* l = (char*)lds;

    // 28 segments, 7 per wave, wave-uniform branches
    if (wid == 0) {
        __builtin_amdgcn_global_load_lds((const void*)(bx1 +    0), (void*)(l + X1O*4 +    0), 16, 0, 0);
        __builtin_amdgcn_global_load_lds((const void*)(bx1 + 1024), (void*)(l + X1O*4 + 1024), 16, 0, 0);
        __builtin_amdgcn_global_load_lds((const void*)(bx1 + 2048), (void*)(l + X1O*4 + 2048), 16, 0, 0);
        __builtin_amdgcn_global_load_lds((const void*)(bg  +    0), (void*)(l + GO*4  +    0), 16, 0, 0);
        __builtin_amdgcn_global_load_lds((const void*)(bg  + 1024), (void*)(l + GO*4  + 1024), 16, 0, 0);
        __builtin_amdgcn_global_load_lds((const void*)(bg  + 2048), (void*)(l + GO*4  + 2048), 16, 0, 0);
        __builtin_amdgcn_global_load_lds((const void*)(bg  + 3072), (void*)(l + GO*4  + 3072), 16, 0, 0);
    } else if (wid == 1) {
        __builtin_amdgcn_global_load_lds((const void*)(bx2 +    0), (void*)(l + X2O*4 +    0), 16, 0, 0);
        __builtin_amdgcn_global_load_lds((const void*)(bx2 + 1024), (void*)(l + X2O*4 + 1024), 16, 0, 0);
        __builtin_amdgcn_global_load_lds((const void*)(bx2 + 2048), (void*)(l + X2O*4 + 2048), 16, 0, 0);
        __builtin_amdgcn_global_load_lds((const void*)(bq1 +    0), (void*)(l + Q1O*4 +    0), 16, 0, 0);
        __builtin_amdgcn_global_load_lds((const void*)(bq1 + 1024), (void*)(l + Q1O*4 + 1024), 16, 0, 0);
        __builtin_amdgcn_global_load_lds((const void*)(bq1 + 2048), (void*)(l + Q1O*4 + 2048), 16, 0, 0);
        __builtin_amdgcn_global_load_lds((const void*)(bq1 + 3072), (void*)(l + Q1O*4 + 3072), 16, 0, 0);
    } else if (wid == 2) {
        __builtin_amdgcn_global_load_lds((const void*)(bx3 +    0), (void*)(l + X3O*4 +    0), 16, 0, 0);
        __builtin_amdgcn_global_load_lds((const void*)(bx3 + 1024), (void*)(l + X3O*4 + 1024), 16, 0, 0);
        __builtin_amdgcn_global_load_lds((const void*)(bx3 + 2048), (void*)(l + X3O*4 + 2048), 16, 0, 0);
        __builtin_amdgcn_global_load_lds((const void*)(bq2 +    0), (void*)(l + Q2O*4 +    0), 16, 0, 0);
        __builtin_amdgcn_global_load_lds((const void*)(bq2 + 1024), (void*)(l + Q2O*4 + 1024), 16, 0, 0);
        __builtin_amdgcn_global_load_lds((const void*)(bq2 + 2048), (void*)(l + Q2O*4 + 2048), 16, 0, 0);
        __builtin_amdgcn_global_load_lds((const void*)(bq2 + 3072), (void*)(l + Q2O*4 + 3072), 16, 0, 0);
    } else {
        __builtin_amdgcn_global_load_lds((const void*)(bg  + 4096), (void*)(l + GO*4  + 4096), 16, 0, 0);
        __builtin_amdgcn_global_load_lds((const void*)(bg  + 5120), (void*)(l + GO*4  + 5120), 16, 0, 0);
        __builtin_amdgcn_global_load_lds((const void*)(bg  + 6144), (void*)(l + GO*4  + 6144), 16, 0, 0);
        __builtin_amdgcn_global_load_lds((const void*)(bq3 +    0), (void*)(l + Q3O*4 +    0), 16, 0, 0);
        __builtin_amdgcn_global_load_lds((const void*)(bq3 + 1024), (void*)(l + Q3O*4 + 1024), 16, 0, 0);
        __builtin_amdgcn_global_load_lds((const void*)(bq3 + 2048), (void*)(l + Q3O*4 + 2048), 16, 0, 0);
        __builtin_amdgcn_global_load_lds((const void*)(bq3 + 3072), (void*)(l + Q3O*4 + 3072), 16, 0, 0);
    }
    __syncthreads();   // drains vmcnt + barrier

    // compute: sample s = tid
    const int s = tid;
    const float px = lds[GO + 7*s + 0];
    const float py = lds[GO + 7*s + 1];
    const float pz = lds[GO + 7*s + 2];
    float qa = lds[GO + 7*s + 3];
    float qb = lds[GO + 7*s + 4];
    float qc = lds[GO + 7*s + 5];
    float qd = lds[GO + 7*s + 6];
    const float qn  = sqrtf(qa*qa + qb*qb + qc*qc + qd*qd);
    const float inv = 1.0f / fmaxf(qn, EPSF);
    qa *= inv; qb *= inv; qc *= inv; qd *= inv;

    float dx, dy, dz, dw;

    dx = lds[X1O + 3*s + 0] - px; dy = lds[X1O + 3*s + 1] - py; dz = lds[X1O + 3*s + 2] - pz;
    const float l1x = sqrtf(dx*dx + dy*dy + dz*dz);
    dw = lds[Q1O + 4*s + 0] - qa; dx = lds[Q1O + 4*s + 1] - qb;
    dy = lds[Q1O + 4*s + 2] - qc; dz = lds[Q1O + 4*s + 3] - qd;
    const float l1q = sqrtf(dw*dw + dx*dx + dy*dy + dz*dz);

    dx = lds[X2O + 3*s + 0] - px; dy = lds[X2O + 3*s + 1] - py; dz = lds[X2O + 3*s + 2] - pz;
    const float l2x = sqrtf(dx*dx + dy*dy + dz*dz);
    dw = lds[Q2O + 4*s + 0] - qa; dx = lds[Q2O + 4*s + 1] - qb;
    dy = lds[Q2O + 4*s + 2] - qc; dz = lds[Q2O + 4*s + 3] - qd;
    const float l2q = sqrtf(dw*dw + dx*dx + dy*dy + dz*dz);

    dx = lds[X3O + 3*s + 0] - px; dy = lds[X3O + 3*s + 1] - py; dz = lds[X3O + 3*s + 2] - pz;
    const float l3x = sqrtf(dx*dx + dy*dy + dz*dz);
    dw = lds[Q3O + 4*s + 0] - qa; dx = lds[Q3O + 4*s + 1] - qb;
    dy = lds[Q3O + 4*s + 2] - qc; dz = lds[Q3O + 4*s + 3] - qd;
    const float l3q = sqrtf(dw*dw + dx*dx + dy*dy + dz*dz);

    float acc = W1_XYZ * (l1x + W1_WPQR * l1q)
              + W2_XYZ * (l2x + W2_WPQR * l2q)
              + W3_XYZ * (l3x + W3_WPQR * l3q);

    // wave-64 reduction
    #pragma unroll
    for (int off = 32; off > 0; off >>= 1)
        acc += __shfl_down(acc, off);

    __shared__ float red[BLOCK / 64];
    if ((tid & 63) == 0) red[wid] = acc;
    __syncthreads();
    if (tid == 0) {
        float ssum = 0.0f;
        #pragma unroll
        for (int w = 0; w < BLOCK / 64; ++w) ssum += red[w];
        partial[blk] = ssum;
    }
}

__global__ __launch_bounds__(BLOCK) void pose_loss_final(
    const float* __restrict__ partial, float* __restrict__ out, int n, float scale)
{
    float acc = 0.0f;
    for (int i = threadIdx.x; i < n; i += BLOCK) acc += partial[i];

    #pragma unroll
    for (int off = 32; off > 0; off >>= 1)
        acc += __shfl_down(acc, off);

    __shared__ float smem[BLOCK / 64];
    const int wid = threadIdx.x >> 6;
    if ((threadIdx.x & 63) == 0) smem[wid] = acc;
    __syncthreads();
    if (threadIdx.x == 0) {
        float s = 0.0f;
        #pragma unroll
        for (int w = 0; w < BLOCK / 64; ++w) s += smem[w];
        out[0] = s * scale;
    }
}

extern "C" void kernel_launch(void* const* d_in, const int* in_sizes, int n_in,
                              void* d_out, int out_size, void* d_ws, size_t ws_size,
                              hipStream_t stream) {
    const float* p1x = (const float*)d_in[0];
    const float* p1q = (const float*)d_in[1];
    const float* p2x = (const float*)d_in[2];
    const float* p2q = (const float*)d_in[3];
    const float* p3x = (const float*)d_in[4];
    const float* p3q = (const float*)d_in[5];
    const float* gt  = (const float*)d_in[6];
    float* out = (float*)d_out;
    float* partial = (float*)d_ws;   // NBLOCKS floats = 16 KB

    pose_loss_partial<<<NBLOCKS, BLOCK, 0, stream>>>(p1x, p1q, p2x, p2q, p3x, p3q, gt, partial);
    pose_loss_final<<<1, BLOCK, 0, stream>>>(partial, out, NBLOCKS, 1.0f / (float)B_TOTAL);
}

// Round 4
// 24.525 us; speedup vs baseline: 1.1488x; 1.1488x over previous
//
#include <hip/hip_runtime.h>

// PoseLoss round 4: barrier-free wave-private staging.
// Each wave owns 256 samples. q streams (16 B/sample, aligned) load directly
// as float4. xyz (12 B) and gt (28 B) streams load as wave-segments
// (lane*16 B dwordx4, perfectly coalesced) into a wave-PRIVATE 16 KB LDS
// region, then read back per-sample (strides 3,7 coprime to 32 banks -> no
// conflicts). No __syncthreads anywhere in the main kernel: all ordering is
// same-wave lgkmcnt. 28 dwordx4 loads/thread -> deep MLP regardless of the
// compiler's register batching (R2 collapsed 28 float2s to VGPR=32).

#define W1_XYZ 0.3f
#define W2_XYZ 0.3f
#define W3_XYZ 1.0f
#define W1_WPQR 150.0f
#define W2_WPQR 150.0f
#define W3_WPQR 500.0f

constexpr int B_TOTAL = 1048576;
constexpr int BLOCK = 256;
constexpr int WPB = 4;                 // waves per block
constexpr int SPW = 256;               // samples per wave
constexpr int NBLOCKS = B_TOTAL / (WPB * SPW);   // 1024
constexpr int NWAVES  = NBLOCKS * WPB;           // 4096

// per-wave LDS: x1,x2,x3 (3072 B each) + gt (7168 B) = 16384 B; block = 64 KiB
constexpr int WAVE_LDS_BYTES = 16384;

__global__ __launch_bounds__(BLOCK) void pose_loss_partial(
    const float* __restrict__ p1x, const float* __restrict__ p1q,
    const float* __restrict__ p2x, const float* __restrict__ p2q,
    const float* __restrict__ p3x, const float* __restrict__ p3q,
    const float* __restrict__ gt, float* __restrict__ partial)
{
    __shared__ __align__(16) char lds[WPB * WAVE_LDS_BYTES];
    const int tid  = threadIdx.x;
    const int wid  = tid >> 6;
    const int lane = tid & 63;
    const long W   = (long)blockIdx.x * WPB + wid;   // global wave id

    float* Lx1 = (float*)(lds + wid * WAVE_LDS_BYTES);  // 768 floats
    float* Lx2 = Lx1 + 768;                              // 768 floats
    float* Lx3 = Lx1 + 1536;                             // 768 floats
    float* Lg  = Lx1 + 2304;                             // 1792 floats

    // ---- direct per-sample q loads: 16 B aligned, lane-contiguous per k ----
    const float4* q1p = (const float4*)p1q;
    const float4* q2p = (const float4*)p2q;
    const float4* q3p = (const float4*)p3q;
    float4 q1v[4], q2v[4], q3v[4];
    #pragma unroll
    for (int k = 0; k < 4; ++k) {
        const long s = W * SPW + (long)(k * 64 + lane);
        q1v[k] = q1p[s];
        q2v[k] = q2p[s];
        q3v[k] = q3p[s];
    }

    // ---- wave-segment loads (lane*16 B) for xyz + gt ----
    // xyz stream bytes per wave = 256*12 = 3072 B = 3 segments of 1024 B
    // gt  stream bytes per wave = 256*28 = 7168 B = 7 segments of 1024 B
    const float4* x1p = (const float4*)p1x;   // float4 idx = 192*W + 64*j + lane
    const float4* x2p = (const float4*)p2x;
    const float4* x3p = (const float4*)p3x;
    const float4* gp  = (const float4*)gt;    // float4 idx = 448*W + 64*j + lane
    float4 xs1[3], xs2[3], xs3[3], gs[7];
    #pragma unroll
    for (int j = 0; j < 3; ++j) xs1[j] = x1p[W * 192 + (long)(j * 64 + lane)];
    #pragma unroll
    for (int j = 0; j < 3; ++j) xs2[j] = x2p[W * 192 + (long)(j * 64 + lane)];
    #pragma unroll
    for (int j = 0; j < 3; ++j) xs3[j] = x3p[W * 192 + (long)(j * 64 + lane)];
    #pragma unroll
    for (int j = 0; j < 7; ++j) gs[j]  = gp [W * 448 + (long)(j * 64 + lane)];

    // redistribute through wave-private LDS (ds_write_b128, stride-16 B: no
    // bank conflicts; no cross-wave sharing -> no barrier needed)
    #pragma unroll
    for (int j = 0; j < 3; ++j) ((float4*)Lx1)[j * 64 + lane] = xs1[j];
    #pragma unroll
    for (int j = 0; j < 3; ++j) ((float4*)Lx2)[j * 64 + lane] = xs2[j];
    #pragma unroll
    for (int j = 0; j < 3; ++j) ((float4*)Lx3)[j * 64 + lane] = xs3[j];
    #pragma unroll
    for (int j = 0; j < 7; ++j) ((float4*)Lg )[j * 64 + lane] = gs[j];

    // ---- compute 4 samples per thread (s = 64k + lane within the wave) ----
    float acc = 0.0f;
    #pragma unroll
    for (int k = 0; k < 4; ++k) {
        const int s = k * 64 + lane;
        const float px = Lg[7*s + 0];
        const float py = Lg[7*s + 1];
        const float pz = Lg[7*s + 2];
        const float qa0 = Lg[7*s + 3];
        const float qb0 = Lg[7*s + 4];
        const float qc0 = Lg[7*s + 5];
        const float qd0 = Lg[7*s + 6];
        // 1/max(sqrt(d), 1e-12) == min(rsq(d), 1e12) for d >= 0
        const float d   = qa0*qa0 + qb0*qb0 + qc0*qc0 + qd0*qd0;
        const float inv = fminf(__builtin_amdgcn_rsqf(d), 1e12f);
        const float qa = qa0 * inv, qb = qb0 * inv, qc = qc0 * inv, qd = qd0 * inv;

        float dx, dy, dz, dw;

        dx = Lx1[3*s + 0] - px; dy = Lx1[3*s + 1] - py; dz = Lx1[3*s + 2] - pz;
        const float l1x = __builtin_amdgcn_sqrtf(dx*dx + dy*dy + dz*dz);
        dw = q1v[k].x - qa; dx = q1v[k].y - qb; dy = q1v[k].z - qc; dz = q1v[k].w - qd;
        const float l1q = __builtin_amdgcn_sqrtf(dw*dw + dx*dx + dy*dy + dz*dz);

        dx = Lx2[3*s + 0] - px; dy = Lx2[3*s + 1] - py; dz = Lx2[3*s + 2] - pz;
        const float l2x = __builtin_amdgcn_sqrtf(dx*dx + dy*dy + dz*dz);
        dw = q2v[k].x - qa; dx = q2v[k].y - qb; dy = q2v[k].z - qc; dz = q2v[k].w - qd;
        const float l2q = __builtin_amdgcn_sqrtf(dw*dw + dx*dx + dy*dy + dz*dz);

        dx = Lx3[3*s + 0] - px; dy = Lx3[3*s + 1] - py; dz = Lx3[3*s + 2] - pz;
        const float l3x = __builtin_amdgcn_sqrtf(dx*dx + dy*dy + dz*dz);
        dw = q3v[k].x - qa; dx = q3v[k].y - qb; dy = q3v[k].z - qc; dz = q3v[k].w - qd;
        const float l3q = __builtin_amdgcn_sqrtf(dw*dw + dx*dx + dy*dy + dz*dz);

        acc += W1_XYZ * (l1x + W1_WPQR * l1q)
             + W2_XYZ * (l2x + W2_WPQR * l2q)
             + W3_XYZ * (l3x + W3_WPQR * l3q);
    }

    // wave-64 reduction -> one partial per WAVE (no block reduce, no barrier)
    #pragma unroll
    for (int off = 32; off > 0; off >>= 1)
        acc += __shfl_down(acc, off);
    if (lane == 0) partial[W] = acc;
}

__global__ __launch_bounds__(1024) void pose_loss_final(
    const float* __restrict__ partial, float* __restrict__ out, float scale)
{
    const int tid = threadIdx.x;
    const float4 v = ((const float4*)partial)[tid];   // 1024 x float4 = 4096 partials
    float acc = (v.x + v.y) + (v.z + v.w);

    #pragma unroll
    for (int off = 32; off > 0; off >>= 1)
        acc += __shfl_down(acc, off);

    __shared__ float smem[16];
    if ((tid & 63) == 0) smem[tid >> 6] = acc;
    __syncthreads();
    if (tid == 0) {
        float s = 0.0f;
        #pragma unroll
        for (int w = 0; w < 16; ++w) s += smem[w];
        out[0] = s * scale;
    }
}

extern "C" void kernel_launch(void* const* d_in, const int* in_sizes, int n_in,
                              void* d_out, int out_size, void* d_ws, size_t ws_size,
                              hipStream_t stream) {
    const float* p1x = (const float*)d_in[0];
    const float* p1q = (const float*)d_in[1];
    const float* p2x = (const float*)d_in[2];
    const float* p2q = (const float*)d_in[3];
    const float* p3x = (const float*)d_in[4];
    const float* p3q = (const float*)d_in[5];
    const float* gt  = (const float*)d_in[6];
    float* out = (float*)d_out;
    float* partial = (float*)d_ws;   // NWAVES floats = 16 KB

    pose_loss_partial<<<NBLOCKS, BLOCK, 0, stream>>>(p1x, p1q, p2x, p2q, p3x, p3q, gt, partial);
    pose_loss_final<<<1, 1024, 0, stream>>>(partial, out, 1.0f / (float)B_TOTAL);
}